// Round 1
// baseline (1180.848 us; speedup 1.0000x reference)
//
#include <hip/hip_runtime.h>
#include <hip/hip_bf16.h>
#include <math.h>

// float32(np.e) exactly: 0x402DF854
#define E32 2.7182817459106445f

// ---------------------------------------------------------------------------
// alpha = max(|tanh(w)|) over each weight tensor (one block per tensor)
// ---------------------------------------------------------------------------
__global__ __launch_bounds__(256) void alpha_kernel(
    const float* w2, int n2, const float* w3, int n3,
    const float* w4, int n4, const float* w5, int n5, float* alphas) {
  const float* w; int n;
  switch (blockIdx.x) {
    case 0: w = w2; n = n2; break;
    case 1: w = w3; n = n3; break;
    case 2: w = w4; n = n4; break;
    default: w = w5; n = n5; break;
  }
  float mx = 0.0f;
  for (int i = threadIdx.x; i < n; i += 256) mx = fmaxf(mx, fabsf(tanhf(w[i])));
  __shared__ float red[256];
  red[threadIdx.x] = mx;
  __syncthreads();
  for (int s = 128; s > 0; s >>= 1) {
    if (threadIdx.x < s) red[threadIdx.x] = fmaxf(red[threadIdx.x], red[threadIdx.x + s]);
    __syncthreads();
  }
  if (threadIdx.x == 0) alphas[blockIdx.x] = red[0];
}

// ---------------------------------------------------------------------------
// Quantize + transpose: wqt[n*F + f] = quant(W[f*N + n])
// quant(w) = rint(clip(tanh(w)/a,-1,1)*127) * a / 127   (round half-to-even)
// ---------------------------------------------------------------------------
__global__ __launch_bounds__(256) void quant_kernel(
    const float* __restrict__ w, const float* __restrict__ alpha,
    float* __restrict__ wqt, int F, int N) {
  int idx = blockIdx.x * 256 + threadIdx.x;
  if (idx >= F * N) return;
  int f = idx / N, n = idx % N;
  float a = alpha[0];
  float t = tanhf(w[idx]);
  float r = fminf(fmaxf(t / a, -1.0f), 1.0f) * 127.0f;
  float rw = rintf(r);
  wqt[n * F + f] = rw * a / 127.0f;
}

// ---------------------------------------------------------------------------
// conv1 (5x5, pad2, stride1, 1->32ch) + BN + ReLU + maxpool2 + min(.,1) + exp
// one thread per z1 element (B,32,32,32)
// ---------------------------------------------------------------------------
__global__ __launch_bounds__(256) void conv1_kernel(
    const float* __restrict__ inp, const float* __restrict__ w,
    const float* __restrict__ g, const float* __restrict__ bb,
    const float* __restrict__ m, const float* __restrict__ vv,
    float* __restrict__ z1) {
  int idx = blockIdx.x * 256 + threadIdx.x;
  if (idx >= 8 * 32 * 32 * 32) return;
  int x = idx & 31, y = (idx >> 5) & 31, c = (idx >> 10) & 31, b = idx >> 15;
  float scale = g[c] / sqrtf(vv[c] + 1e-5f);
  float bias = bb[c];
  float mean = m[c];
  float mx = -3.402823466e38f;
  for (int dy = 0; dy < 2; ++dy) {
    for (int dx = 0; dx < 2; ++dx) {
      int oy = 2 * y + dy, ox = 2 * x + dx;
      float acc = 0.0f;
      for (int kh = 0; kh < 5; ++kh) {
        int r = oy + kh - 2;
        if (r < 0 || r >= 64) continue;
        for (int kw = 0; kw < 5; ++kw) {
          int cc2 = ox + kw - 2;
          if (cc2 < 0 || cc2 >= 64) continue;
          acc += w[c * 25 + kh * 5 + kw] * inp[(b * 64 + r) * 64 + cc2];
        }
      }
      float xs = (acc - mean) * scale + bias;
      xs = fmaxf(xs, 0.0f);
      mx = fmaxf(mx, xs);
    }
  }
  mx = fminf(mx, 1.0f);
  // exact float32(e) on saturation so sort-ties against MAX_Z padding match jax
  z1[idx] = (mx == 1.0f) ? E32 : expf(mx);
}

// ---------------------------------------------------------------------------
// min_pool3: 3x3 window, stride 2, pad 1 (pad value 1e5)
// ---------------------------------------------------------------------------
__global__ __launch_bounds__(256) void mp3_kernel(
    const float* __restrict__ in, float* __restrict__ out, int BC, int H) {
  int OH = H >> 1;
  int total = BC * OH * OH;
  int idx = blockIdx.x * 256 + threadIdx.x;
  if (idx >= total) return;
  int j = idx % OH, i = (idx / OH) % OH, bc = idx / (OH * OH);
  float mn = 100000.0f;
  for (int di = 0; di < 3; ++di) {
    int r = 2 * i - 1 + di;
    if (r < 0 || r >= H) continue;
    for (int dj = 0; dj < 3; ++dj) {
      int cc = 2 * j - 1 + dj;
      if (cc < 0 || cc >= H) continue;
      mn = fminf(mn, in[bc * H * H + r * H + cc]);
    }
  }
  out[idx] = mn;
}

__global__ __launch_bounds__(256) void mul_kernel(
    const float* __restrict__ a, const float* __restrict__ b,
    float* __restrict__ o, int n) {
  int idx = blockIdx.x * 256 + threadIdx.x;
  if (idx < n) o[idx] = a[idx] * b[idx];
}

// ---------------------------------------------------------------------------
// t_conv: one wave (64 threads) per patch.
//  Phase 0: compute patch values (with <0.1 -> MST) into LDS
//  Phase 1: stable rank sort (value asc, original index asc)
//  Phase 2: gathered-chunk weight staging + sequential cumsum scan per channel
// Output layout (B, F, OH, OW) = transpose(0,2,1) of t_linear_c output.
// ---------------------------------------------------------------------------
template <int CIN, int F, int S, int HIN>
__global__ __launch_bounds__(64) void tconv_kernel(
    const float* __restrict__ in, const float* __restrict__ wqt,
    float* __restrict__ out, float MST) {
  constexpr int N = CIN * 9;
  constexpr int OH = (HIN - 1) / S + 1;
  constexpr int P = OH * OH;
  constexpr int CH = (N * F <= 9216) ? N : (9216 / F);

  __shared__ float pv[N];
  __shared__ float sval[N];
  __shared__ unsigned short sidx[N];
  __shared__ float wbuf[CH * F];

  int blk = blockIdx.x;
  int b = blk / P, p = blk % P;
  int ph = p / OH, pw = p % OH;
  int tid = threadIdx.x;

  // Phase 0: patch values (unfold order: c*9 + kh*3 + kw), pad=1
  for (int n = tid; n < N; n += 64) {
    int c = n / 9, kk = n % 9, kh = kk / 3, kw = kk % 3;
    int r = ph * S + kh - 1, cc = pw * S + kw - 1;
    float v = 0.0f;
    if (r >= 0 && r < HIN && cc >= 0 && cc < HIN)
      v = in[((b * CIN + c) * HIN + r) * HIN + cc];
    pv[n] = (v < 0.1f) ? MST : v;
  }
  __syncthreads();

  // Phase 1: stable rank sort
  constexpr int K = (N + 63) / 64;
  float v[K];
  int rnk[K];
#pragma unroll
  for (int k = 0; k < K; ++k) {
    int i = tid + 64 * k;
    v[k] = (i < N) ? pv[i] : 0.0f;
    rnk[k] = 0;
  }
  for (int j = 0; j < N; ++j) {
    float u = pv[j];
#pragma unroll
    for (int k = 0; k < K; ++k) {
      int i = tid + 64 * k;
      rnk[k] += (u < v[k] || (u == v[k] && j < i)) ? 1 : 0;
    }
  }
#pragma unroll
  for (int k = 0; k < K; ++k) {
    int i = tid + 64 * k;
    if (i < N) {
      sval[rnk[k]] = v[k];
      sidx[rnk[k]] = (unsigned short)i;
    }
  }
  __syncthreads();

  // Phase 2: sequential spike-time scan (lane = output channel)
  float wsum = 0.0f, iwsum = 0.0f, omin = 3.402823466e38f;
  for (int c0 = 0; c0 < N; c0 += CH) {
    int cnt = (N - c0 < CH) ? (N - c0) : CH;
    for (int t = tid; t < cnt * F; t += 64) {
      int ii = c0 + t / F, ff = t % F;
      wbuf[t] = wqt[(int)sidx[ii] * F + ff];
    }
    __syncthreads();
    if (tid < F) {
      for (int q = 0; q < cnt; ++q) {
        int i = c0 + q;
        float s = sval[i];
        float nxt = (i + 1 < N) ? sval[i + 1] : 1.0f;
        float w = wbuf[q * F + tid];
        wsum = __fadd_rn(wsum, w);
        iwsum = __fadd_rn(iwsum, __fmul_rn(s, w));
        float den = fminf(fmaxf(__fadd_rn(wsum, -1.0f), 1e-10f), 1e10f);
        float oa = iwsum / den;
        float o = (wsum < 1.0f) ? MST : oa;
        o = (o < s) ? MST : o;
        o = (o > nxt) ? MST : o;   // t_linear_c: strict >
        omin = fminf(omin, o);
      }
    }
    __syncthreads();
  }
  if (tid < F) out[(b * F + tid) * P + p] = omin;
}

// ---------------------------------------------------------------------------
// Final t_linear (FC): per batch row, bitonic sort of 4096 (val,idx) u64 keys,
// then sequential scan over 10 output neurons (raw W, o >= nxt rule).
// Input feature n = c*64 + p : z5[b,c,p] * m3[b, c&31, p]
// ---------------------------------------------------------------------------
__device__ __forceinline__ unsigned long long packkey(float vf, int idx) {
  unsigned u = __float_as_uint(vf);
  u = (u & 0x80000000u) ? ~u : (u | 0x80000000u);
  return (((unsigned long long)u) << 32) | (unsigned)idx;
}
__device__ __forceinline__ float unpackval(unsigned long long k) {
  unsigned m = (unsigned)(k >> 32);
  m = (m & 0x80000000u) ? (m ^ 0x80000000u) : ~m;
  return __uint_as_float(m);
}

__global__ __launch_bounds__(256) void fc_kernel(
    const float* __restrict__ z5, const float* __restrict__ m3,
    const float* __restrict__ wfc, float* __restrict__ out) {
  constexpr int NN = 4096;
  __shared__ unsigned long long keys[NN];
  __shared__ float wbuf[256 * 10];
  int b = blockIdx.x;
  int tid = threadIdx.x;

  for (int n = tid; n < NN; n += 256) {
    int c = n >> 6, p = n & 63;
    float vf = __fmul_rn(z5[(b * 64 + c) * 64 + p],
                         m3[(b * 32 + (c & 31)) * 64 + p]);
    keys[n] = packkey(vf, n);
  }
  __syncthreads();

  // bitonic sort ascending
  for (int k = 2; k <= NN; k <<= 1) {
    for (int j = k >> 1; j > 0; j >>= 1) {
      for (int i = tid; i < NN; i += 256) {
        int ixj = i ^ j;
        if (ixj > i) {
          unsigned long long a = keys[i], c2 = keys[ixj];
          bool up = ((i & k) == 0);
          if ((a > c2) == up) { keys[i] = c2; keys[ixj] = a; }
        }
      }
      __syncthreads();
    }
  }

  const float MST = 4.0f * E32;
  float wsum = 0.0f, iwsum = 0.0f, omin = 3.402823466e38f;
  for (int c0 = 0; c0 < NN; c0 += 256) {
    for (int t = tid; t < 256 * 10; t += 256) {
      int ii = c0 + t / 10, ff = t % 10;
      unsigned jdx = (unsigned)(keys[ii] & 0xFFFFFFFFull);
      wbuf[t] = wfc[ff * 4096 + jdx];
    }
    __syncthreads();
    if (tid < 10) {
      for (int q = 0; q < 256; ++q) {
        int i = c0 + q;
        float s = unpackval(keys[i]);
        float nxt = (i + 1 < NN) ? unpackval(keys[i + 1]) : 1.0f;
        float w = wbuf[q * 10 + tid];
        wsum = __fadd_rn(wsum, w);
        iwsum = __fadd_rn(iwsum, __fmul_rn(s, w));
        float den = fminf(fmaxf(__fadd_rn(wsum, -1.0f), 1e-10f), 1e10f);
        float oa = iwsum / den;
        float o = (wsum < 1.0f) ? MST : oa;
        o = (o < s) ? MST : o;
        o = (o >= nxt) ? MST : o;   // t_linear: >=
        omin = fminf(omin, o);
      }
    }
    __syncthreads();
  }
  if (tid < 10) out[b * 10 + tid] = omin;
}

// ---------------------------------------------------------------------------
extern "C" void kernel_launch(void* const* d_in, const int* in_sizes, int n_in,
                              void* d_out, int out_size, void* d_ws, size_t ws_size,
                              hipStream_t stream) {
  const float* inp   = (const float*)d_in[0];
  const float* w1    = (const float*)d_in[1];
  const float* bn_g  = (const float*)d_in[2];
  const float* bn_b  = (const float*)d_in[3];
  const float* bn_m  = (const float*)d_in[4];
  const float* bn_v  = (const float*)d_in[5];
  const float* w2    = (const float*)d_in[6];
  const float* w3    = (const float*)d_in[7];
  const float* w4    = (const float*)d_in[8];
  const float* w5    = (const float*)d_in[9];
  const float* wfc   = (const float*)d_in[10];
  float* out = (float*)d_out;

  float* ws = (float*)d_ws;
  float* alphas = ws;            // 4
  float* wq2 = ws + 16;          // 288*32 = 9216
  float* wq3 = wq2 + 9216;       // 9216
  float* wq4 = wq3 + 9216;       // 288*64 = 18432
  float* wq5 = wq4 + 18432;      // 576*64 = 36864
  float* z1  = wq5 + 36864;      // 8*32*32*32 = 262144
  float* m1  = z1 + 262144;      // 8*32*16*16 = 65536
  float* z2  = m1 + 65536;       // 65536
  float* z3  = z2 + 65536;       // 65536
  float* z3c = z3 + 65536;       // 65536
  float* m3  = z3c + 65536;      // 8*32*8*8 = 16384
  float* z4  = m3 + 16384;       // 8*64*8*8 = 32768
  float* z5  = z4 + 32768;       // 32768

  // weight quantization (once per call; inputs never mutated)
  alpha_kernel<<<4, 256, 0, stream>>>(w2, 9216, w3, 9216, w4, 18432, w5, 36864, alphas);
  quant_kernel<<<(9216 + 255) / 256, 256, 0, stream>>>(w2, alphas + 0, wq2, 32, 288);
  quant_kernel<<<(9216 + 255) / 256, 256, 0, stream>>>(w3, alphas + 1, wq3, 32, 288);
  quant_kernel<<<(18432 + 255) / 256, 256, 0, stream>>>(w4, alphas + 2, wq4, 64, 288);
  quant_kernel<<<(36864 + 255) / 256, 256, 0, stream>>>(w5, alphas + 3, wq5, 64, 576);

  // front end
  conv1_kernel<<<(262144 + 255) / 256, 256, 0, stream>>>(inp, w1, bn_g, bn_b, bn_m, bn_v, z1);
  mp3_kernel<<<(65536 + 255) / 256, 256, 0, stream>>>(z1, m1, 8 * 32, 32);

  // spiking conv stack
  tconv_kernel<32, 32, 2, 32><<<8 * 256, 64, 0, stream>>>(z1, wq2, z2, E32);
  tconv_kernel<32, 32, 1, 16><<<8 * 256, 64, 0, stream>>>(z2, wq3, z3, E32);
  mul_kernel<<<(65536 + 255) / 256, 256, 0, stream>>>(z3, m1, z3c, 65536);
  mp3_kernel<<<(16384 + 255) / 256, 256, 0, stream>>>(z3c, m3, 8 * 32, 16);
  tconv_kernel<32, 64, 2, 16><<<8 * 64, 64, 0, stream>>>(z3c, wq4, z4, 2.0f * E32);
  tconv_kernel<64, 64, 1, 8><<<8 * 64, 64, 0, stream>>>(z4, wq5, z5, 2.0f * E32);

  // final t_linear
  fc_kernel<<<8, 256, 0, stream>>>(z5, m3, wfc, out);
}

// Round 2
// 473.777 us; speedup vs baseline: 2.4924x; 2.4924x over previous
//
#include <hip/hip_runtime.h>
#include <hip/hip_bf16.h>
#include <math.h>

// float32(np.e) exactly: 0x402DF854
#define E32 2.7182817459106445f

__device__ __forceinline__ unsigned long long packkey(float vf, int idx) {
  unsigned u = __float_as_uint(vf);
  u = (u & 0x80000000u) ? ~u : (u | 0x80000000u);
  return (((unsigned long long)u) << 32) | (unsigned)idx;
}
__device__ __forceinline__ float unpackval(unsigned long long k) {
  unsigned m = (unsigned)(k >> 32);
  m = (m & 0x80000000u) ? (m ^ 0x80000000u) : ~m;
  return __uint_as_float(m);
}

// ---------------------------------------------------------------------------
// alpha = max(|tanh(w)|) over each weight tensor (one block per tensor)
// ---------------------------------------------------------------------------
__global__ __launch_bounds__(256) void alpha_kernel(
    const float* w2, int n2, const float* w3, int n3,
    const float* w4, int n4, const float* w5, int n5, float* alphas) {
  const float* w; int n;
  switch (blockIdx.x) {
    case 0: w = w2; n = n2; break;
    case 1: w = w3; n = n3; break;
    case 2: w = w4; n = n4; break;
    default: w = w5; n = n5; break;
  }
  float mx = 0.0f;
  for (int i = threadIdx.x; i < n; i += 256) mx = fmaxf(mx, fabsf(tanhf(w[i])));
  __shared__ float red[256];
  red[threadIdx.x] = mx;
  __syncthreads();
  for (int s = 128; s > 0; s >>= 1) {
    if (threadIdx.x < s) red[threadIdx.x] = fmaxf(red[threadIdx.x], red[threadIdx.x + s]);
    __syncthreads();
  }
  if (threadIdx.x == 0) alphas[blockIdx.x] = red[0];
}

// ---------------------------------------------------------------------------
// Quantize + transpose: wqt[n*F + f] = quant(W[f*N + n])
// ---------------------------------------------------------------------------
__global__ __launch_bounds__(256) void quant_kernel(
    const float* __restrict__ w, const float* __restrict__ alpha,
    float* __restrict__ wqt, int F, int N) {
  int idx = blockIdx.x * 256 + threadIdx.x;
  if (idx >= F * N) return;
  int f = idx / N, n = idx % N;
  float a = alpha[0];
  float t = tanhf(w[idx]);
  float r = fminf(fmaxf(t / a, -1.0f), 1.0f) * 127.0f;
  float rw = rintf(r);
  wqt[n * F + f] = rw * a / 127.0f;
}

// ---------------------------------------------------------------------------
// conv1 + BN + ReLU + maxpool2 + min(.,1) + exp  (unchanged — bit-exact pass)
// ---------------------------------------------------------------------------
__global__ __launch_bounds__(256) void conv1_kernel(
    const float* __restrict__ inp, const float* __restrict__ w,
    const float* __restrict__ g, const float* __restrict__ bb,
    const float* __restrict__ m, const float* __restrict__ vv,
    float* __restrict__ z1) {
  int idx = blockIdx.x * 256 + threadIdx.x;
  if (idx >= 8 * 32 * 32 * 32) return;
  int x = idx & 31, y = (idx >> 5) & 31, c = (idx >> 10) & 31, b = idx >> 15;
  float scale = g[c] / sqrtf(vv[c] + 1e-5f);
  float bias = bb[c];
  float mean = m[c];
  float mx = -3.402823466e38f;
  for (int dy = 0; dy < 2; ++dy) {
    for (int dx = 0; dx < 2; ++dx) {
      int oy = 2 * y + dy, ox = 2 * x + dx;
      float acc = 0.0f;
      for (int kh = 0; kh < 5; ++kh) {
        int r = oy + kh - 2;
        if (r < 0 || r >= 64) continue;
        for (int kw = 0; kw < 5; ++kw) {
          int cc2 = ox + kw - 2;
          if (cc2 < 0 || cc2 >= 64) continue;
          acc += w[c * 25 + kh * 5 + kw] * inp[(b * 64 + r) * 64 + cc2];
        }
      }
      float xs = (acc - mean) * scale + bias;
      xs = fmaxf(xs, 0.0f);
      mx = fmaxf(mx, xs);
    }
  }
  mx = fminf(mx, 1.0f);
  z1[idx] = (mx == 1.0f) ? E32 : expf(mx);
}

// ---------------------------------------------------------------------------
// min_pool3: 3x3 window, stride 2, pad 1 (pad value 1e5)
// ---------------------------------------------------------------------------
__global__ __launch_bounds__(256) void mp3_kernel(
    const float* __restrict__ in, float* __restrict__ out, int BC, int H) {
  int OH = H >> 1;
  int total = BC * OH * OH;
  int idx = blockIdx.x * 256 + threadIdx.x;
  if (idx >= total) return;
  int j = idx % OH, i = (idx / OH) % OH, bc = idx / (OH * OH);
  float mn = 100000.0f;
  for (int di = 0; di < 3; ++di) {
    int r = 2 * i - 1 + di;
    if (r < 0 || r >= H) continue;
    for (int dj = 0; dj < 3; ++dj) {
      int cc = 2 * j - 1 + dj;
      if (cc < 0 || cc >= H) continue;
      mn = fminf(mn, in[bc * H * H + r * H + cc]);
    }
  }
  out[idx] = mn;
}

__global__ __launch_bounds__(256) void mul_kernel(
    const float* __restrict__ a, const float* __restrict__ b,
    float* __restrict__ o, int n) {
  int idx = blockIdx.x * 256 + threadIdx.x;
  if (idx < n) o[idx] = a[idx] * b[idx];
}

// ---------------------------------------------------------------------------
// t_conv: one block (T=128 threads) per patch.
//  Phase 0: packed (value,idx) u64 keys in LDS
//  Phase 1: stable rank sort via single u64 compare per pair (batched reads)
//  Phase 2: gathered-chunk weight staging + batched sequential scan
// ---------------------------------------------------------------------------
template <int CIN, int F, int S, int HIN, int T>
__global__ __launch_bounds__(T) void tconv_kernel(
    const float* __restrict__ in, const float* __restrict__ wqt,
    float* __restrict__ out, float MST) {
  constexpr int N = CIN * 9;
  constexpr int OH = (HIN - 1) / S + 1;
  constexpr int P = OH * OH;
  constexpr int CH = (N * F <= 9216) ? N : (9216 / F);

  __shared__ unsigned long long pk[N];
  __shared__ float sval[N + 1];
  __shared__ unsigned short sidx[N];
  __shared__ float wbuf[CH * F];

  int blk = blockIdx.x;
  int b = blk / P, p = blk % P;
  int ph = p / OH, pw = p % OH;
  int tid = threadIdx.x;

  // Phase 0: patch values (unfold order: c*9 + kh*3 + kw), pad=1
  for (int n = tid; n < N; n += T) {
    int c = n / 9, kk = n % 9, kh = kk / 3, kw = kk % 3;
    int r = ph * S + kh - 1, cc = pw * S + kw - 1;
    float v = 0.0f;
    if (r >= 0 && r < HIN && cc >= 0 && cc < HIN)
      v = in[((b * CIN + c) * HIN + r) * HIN + cc];
    pk[n] = packkey((v < 0.1f) ? MST : v, n);
  }
  if (tid == 0) sval[N] = 1.0f;  // nxt sentinel for last element
  __syncthreads();

  // Phase 1: stable rank sort (u64 keys: value asc, index asc)
  constexpr int K = (N + T - 1) / T;
  unsigned long long kv[K];
  int rnk[K];
#pragma unroll
  for (int k = 0; k < K; ++k) {
    int i = tid + T * k;
    kv[k] = (i < N) ? pk[i] : ~0ull;
    rnk[k] = 0;
  }
  for (int j0 = 0; j0 < N; j0 += 8) {  // N % 8 == 0
    unsigned long long u[8];
#pragma unroll
    for (int r = 0; r < 8; ++r) u[r] = pk[j0 + r];
#pragma unroll
    for (int r = 0; r < 8; ++r) {
#pragma unroll
      for (int k = 0; k < K; ++k) rnk[k] += (u[r] < kv[k]) ? 1 : 0;
    }
  }
#pragma unroll
  for (int k = 0; k < K; ++k) {
    int i = tid + T * k;
    if (i < N) {
      sval[rnk[k]] = unpackval(kv[k]);
      sidx[rnk[k]] = (unsigned short)(kv[k] & 0xffffull);
    }
  }
  __syncthreads();

  // Phase 2: sequential spike-time scan (lane = output channel), batched loads
  float wsum = 0.0f, iwsum = 0.0f, omin = 3.402823466e38f;
  for (int c0 = 0; c0 < N; c0 += CH) {
    constexpr int CNT = (CH < N) ? CH : N;  // always == CH
    for (int t = tid; t < CNT * F; t += T) {
      int ii = c0 + t / F, ff = t % F;
      wbuf[t] = wqt[(int)sidx[ii] * F + ff];
    }
    __syncthreads();
    if (tid < F) {
      for (int q0 = 0; q0 < CNT; q0 += 8) {  // CNT % 8 == 0 (288 or 144)
        float wv[8], sv[8], nv[8];
#pragma unroll
        for (int r = 0; r < 8; ++r) {
          int i = c0 + q0 + r;
          wv[r] = wbuf[(q0 + r) * F + tid];
          sv[r] = sval[i];
          nv[r] = sval[i + 1];
        }
#pragma unroll
        for (int r = 0; r < 8; ++r) {
          wsum = __fadd_rn(wsum, wv[r]);
          iwsum = __fadd_rn(iwsum, __fmul_rn(sv[r], wv[r]));
          float den = fminf(fmaxf(__fadd_rn(wsum, -1.0f), 1e-10f), 1e10f);
          float oa = iwsum / den;
          float o = (wsum < 1.0f) ? MST : oa;
          o = (o < sv[r]) ? MST : o;
          o = (o > nv[r]) ? MST : o;  // t_linear_c: strict >
          omin = fminf(omin, o);
        }
      }
    }
    __syncthreads();
  }
  if (tid < F) out[(b * F + tid) * P + p] = omin;
}

// ---------------------------------------------------------------------------
// Final t_linear (FC): bitonic sort of 4096 (val,idx) keys, then
// carry pass (exact sequential wsum/iwsum chains, carries every 128) +
// parallel bit-exact replay of 32 chunks x 10 neurons on 320 threads.
// ---------------------------------------------------------------------------
__global__ __launch_bounds__(512) void fc_kernel(
    const float* __restrict__ z5, const float* __restrict__ m3,
    const float* __restrict__ wfc, float* __restrict__ out) {
  constexpr int NN = 4096;
  __shared__ unsigned long long keys[NN];   // 32 KB
  __shared__ float sval[NN + 1];            // 16 KB
  __shared__ unsigned short sidx[NN];       // 8 KB
  __shared__ float wc[32][10];
  __shared__ float iwc[32][10];
  __shared__ float pmin[32][10];
  int b = blockIdx.x;
  int tid = threadIdx.x;

  for (int n = tid; n < NN; n += 512) {
    int c = n >> 6, p = n & 63;
    float vf = __fmul_rn(z5[(b * 64 + c) * 64 + p],
                         m3[(b * 32 + (c & 31)) * 64 + p]);
    keys[n] = packkey(vf, n);
  }
  __syncthreads();

  // bitonic sort ascending
  for (int k = 2; k <= NN; k <<= 1) {
    for (int j = k >> 1; j > 0; j >>= 1) {
      for (int i = tid; i < NN; i += 512) {
        int ixj = i ^ j;
        if (ixj > i) {
          unsigned long long a = keys[i], c2 = keys[ixj];
          bool up = ((i & k) == 0);
          if ((a > c2) == up) { keys[i] = c2; keys[ixj] = a; }
        }
      }
      __syncthreads();
    }
  }

  // extract
  for (int n = tid; n < NN; n += 512) {
    unsigned long long kk = keys[n];
    sval[n] = unpackval(kk);
    sidx[n] = (unsigned short)(kk & 0xffffull);
  }
  if (tid == 0) sval[NN] = 1.0f;
  __syncthreads();

  // carry pass: exact sequential wsum/iwsum chains, exclusive carry per 128
  if (tid < 10) {
    const float* __restrict__ wrow = wfc + tid * NN;
    float wsum = 0.0f, iwsum = 0.0f;
    for (int c = 0; c < 32; ++c) {
      wc[c][tid] = wsum;
      iwc[c][tid] = iwsum;
      int i0 = c * 128;
      for (int q0 = 0; q0 < 128; q0 += 16) {
        int idx16[16];
        float wv[16];
#pragma unroll
        for (int r = 0; r < 16; ++r) idx16[r] = sidx[i0 + q0 + r];
#pragma unroll
        for (int r = 0; r < 16; ++r) wv[r] = wrow[idx16[r]];
#pragma unroll
        for (int r = 0; r < 16; ++r) {
          wsum = __fadd_rn(wsum, wv[r]);
          iwsum = __fadd_rn(iwsum, __fmul_rn(sval[i0 + q0 + r], wv[r]));
        }
      }
    }
  }
  __syncthreads();

  // replay: 320 parallel tasks (chunk c, neuron f), bit-exact per element
  const float MST = 4.0f * E32;
  if (tid < 320) {
    int c = tid / 10, f = tid % 10;
    const float* __restrict__ wrow = wfc + f * NN;
    float wsum = wc[c][f], iwsum = iwc[c][f], omin = 3.402823466e38f;
    int i0 = c * 128;
    for (int q0 = 0; q0 < 128; q0 += 8) {
      float wv[8], sv[8], nv[8];
#pragma unroll
      for (int r = 0; r < 8; ++r) {
        int i = i0 + q0 + r;
        wv[r] = wrow[sidx[i]];
        sv[r] = sval[i];
        nv[r] = sval[i + 1];
      }
#pragma unroll
      for (int r = 0; r < 8; ++r) {
        wsum = __fadd_rn(wsum, wv[r]);
        iwsum = __fadd_rn(iwsum, __fmul_rn(sv[r], wv[r]));
        float den = fminf(fmaxf(__fadd_rn(wsum, -1.0f), 1e-10f), 1e10f);
        float oa = iwsum / den;
        float o = (wsum < 1.0f) ? MST : oa;
        o = (o < sv[r]) ? MST : o;
        o = (o >= nv[r]) ? MST : o;  // t_linear: >=
        omin = fminf(omin, o);
      }
    }
    pmin[c][f] = omin;
  }
  __syncthreads();

  // min across chunks (exact, order-free)
  if (tid < 10) {
    float m = pmin[0][tid];
#pragma unroll
    for (int c = 1; c < 32; ++c) m = fminf(m, pmin[c][tid]);
    out[b * 10 + tid] = m;
  }
}

// ---------------------------------------------------------------------------
extern "C" void kernel_launch(void* const* d_in, const int* in_sizes, int n_in,
                              void* d_out, int out_size, void* d_ws, size_t ws_size,
                              hipStream_t stream) {
  const float* inp   = (const float*)d_in[0];
  const float* w1    = (const float*)d_in[1];
  const float* bn_g  = (const float*)d_in[2];
  const float* bn_b  = (const float*)d_in[3];
  const float* bn_m  = (const float*)d_in[4];
  const float* bn_v  = (const float*)d_in[5];
  const float* w2    = (const float*)d_in[6];
  const float* w3    = (const float*)d_in[7];
  const float* w4    = (const float*)d_in[8];
  const float* w5    = (const float*)d_in[9];
  const float* wfc   = (const float*)d_in[10];
  float* out = (float*)d_out;

  float* ws = (float*)d_ws;
  float* alphas = ws;            // 4
  float* wq2 = ws + 16;          // 288*32 = 9216
  float* wq3 = wq2 + 9216;       // 9216
  float* wq4 = wq3 + 9216;       // 288*64 = 18432
  float* wq5 = wq4 + 18432;      // 576*64 = 36864
  float* z1  = wq5 + 36864;      // 8*32*32*32 = 262144
  float* m1  = z1 + 262144;      // 8*32*16*16 = 65536
  float* z2  = m1 + 65536;       // 65536
  float* z3  = z2 + 65536;       // 65536
  float* z3c = z3 + 65536;       // 65536
  float* m3  = z3c + 65536;      // 8*32*8*8 = 16384
  float* z4  = m3 + 16384;       // 8*64*8*8 = 32768
  float* z5  = z4 + 32768;       // 32768

  // weight quantization
  alpha_kernel<<<4, 256, 0, stream>>>(w2, 9216, w3, 9216, w4, 18432, w5, 36864, alphas);
  quant_kernel<<<(9216 + 255) / 256, 256, 0, stream>>>(w2, alphas + 0, wq2, 32, 288);
  quant_kernel<<<(9216 + 255) / 256, 256, 0, stream>>>(w3, alphas + 1, wq3, 32, 288);
  quant_kernel<<<(18432 + 255) / 256, 256, 0, stream>>>(w4, alphas + 2, wq4, 64, 288);
  quant_kernel<<<(36864 + 255) / 256, 256, 0, stream>>>(w5, alphas + 3, wq5, 64, 576);

  // front end
  conv1_kernel<<<(262144 + 255) / 256, 256, 0, stream>>>(inp, w1, bn_g, bn_b, bn_m, bn_v, z1);
  mp3_kernel<<<(65536 + 255) / 256, 256, 0, stream>>>(z1, m1, 8 * 32, 32);

  // spiking conv stack
  tconv_kernel<32, 32, 2, 32, 128><<<8 * 256, 128, 0, stream>>>(z1, wq2, z2, E32);
  tconv_kernel<32, 32, 1, 16, 128><<<8 * 256, 128, 0, stream>>>(z2, wq3, z3, E32);
  mul_kernel<<<(65536 + 255) / 256, 256, 0, stream>>>(z3, m1, z3c, 65536);
  mp3_kernel<<<(16384 + 255) / 256, 256, 0, stream>>>(z3c, m3, 8 * 32, 16);
  tconv_kernel<32, 64, 2, 16, 128><<<8 * 64, 128, 0, stream>>>(z3c, wq4, z4, 2.0f * E32);
  tconv_kernel<64, 64, 1, 8, 128><<<8 * 64, 128, 0, stream>>>(z4, wq5, z5, 2.0f * E32);

  // final t_linear
  fc_kernel<<<8, 512, 0, stream>>>(z5, m3, wfc, out);
}